// Round 5
// baseline (229.296 us; speedup 1.0000x reference)
//
#include <hip/hip_runtime.h>

#define NJ 24
#define NF 7
#define FS 6
#define THREADS 256
#define CUNITS 12   // float4 per thread per chunk (4 joint-pairs = 192 B)
#define PAD 13      // LDS stride in float4 units

typedef float v4f __attribute__((ext_vector_type(4)));

// parent of each joint; parents[i] < i, so sequential order is topological
__device__ constexpr int kParents[NJ] = {-1, 0, 0, 0, 1, 2, 3, 4, 5, 6, 7, 8,
                                          9, 9, 9, 12, 13, 14, 16, 17, 18, 19, 20, 21};

// Compute joint i for one sample; stage completed joint-pairs into LDS.
// Macro (not function) so all indexing stays compile-time after unrolling.
#define JOINT(i, XR, FEATS, MYSTAGE)                                          \
    {                                                                         \
        const int p_ = kParents[i];                                           \
        float inp_[NF];                                                       \
        inp_[0] = XR[i];                                                      \
        _Pragma("unroll")                                                     \
        for (int j = 0; j < FS; ++j)                                          \
            inp_[1 + j] = (p_ < 0) ? 0.0f : FEATS[(p_ < 0) ? 0 : p_][j];      \
        float h_[NF];                                                         \
        _Pragma("unroll")                                                     \
        for (int j = 0; j < NF; ++j) h_[j] = b1[(i) * NF + j];                \
        _Pragma("unroll")                                                     \
        for (int k = 0; k < NF; ++k) {                                        \
            const float a_ = inp_[k];                                         \
            _Pragma("unroll")                                                 \
            for (int j = 0; j < NF; ++j)                                      \
                h_[j] = fmaf(a_, W1[(i) * NF * NF + k * NF + j], h_[j]);      \
        }                                                                     \
        _Pragma("unroll")                                                     \
        for (int j = 0; j < NF; ++j) h_[j] = fmaxf(h_[j], 0.0f);              \
        float f_[FS];                                                         \
        _Pragma("unroll")                                                     \
        for (int j = 0; j < FS; ++j) f_[j] = b2[(i) * FS + j];                \
        _Pragma("unroll")                                                     \
        for (int k = 0; k < NF; ++k) {                                        \
            const float a_ = h_[k];                                           \
            _Pragma("unroll")                                                 \
            for (int j = 0; j < FS; ++j)                                      \
                f_[j] = fmaf(a_, W2[(i) * NF * FS + k * FS + j], f_[j]);      \
        }                                                                     \
        _Pragma("unroll")                                                     \
        for (int j = 0; j < FS; ++j) {                                        \
            f_[j] = fmaxf(f_[j], 0.0f);                                       \
            FEATS[i][j] = f_[j];                                              \
        }                                                                     \
        if ((i) & 1) { /* stage pair (i-1, i): 3 x float4 */                  \
            const int pp_ = ((i) >> 1) & 3;                                   \
            float4* st_ = (MYSTAGE) + pp_ * 3;                                \
            st_[0] = make_float4(FEATS[(i) - 1][0], FEATS[(i) - 1][1],        \
                                 FEATS[(i) - 1][2], FEATS[(i) - 1][3]);       \
            st_[1] = make_float4(FEATS[(i) - 1][4], FEATS[(i) - 1][5],        \
                                 f_[0], f_[1]);                               \
            st_[2] = make_float4(f_[2], f_[3], f_[4], f_[5]);                 \
        }                                                                     \
    }

// Flush: 12 wave-stores, each = 16 complete 64B lines (proven R3).
// Nontemporal: out is a write-once stream; keep it out of L2/L3.
#define FLUSH(WB, C)                                                          \
    {                                                                         \
        _Pragma("unroll")                                                     \
        for (int j = 0; j < CUNITS; ++j) {                                    \
            float4 v = sm[wid][su[j]];                                        \
            v4f* dst_ = reinterpret_cast<v4f*>(                               \
                outv + (size_t)(WB) * 36 + (C) * 12 + ro[j]);                 \
            __builtin_nontemporal_store(*reinterpret_cast<v4f*>(&v), dst_);   \
        }                                                                     \
    }

// Requires B % 512 == 0 (bench: B = 524288).
__global__ __launch_bounds__(THREADS, 3) void se1d_kernel(
    const float* __restrict__ x,
    const float* __restrict__ W1,
    const float* __restrict__ b1,
    const float* __restrict__ W2,
    const float* __restrict__ b2,
    float* __restrict__ out, int B)
{
    // Wave-private staging: 64 lanes x 13 float4 = 13312 B/wave, 53 KB/block
    // -> 3 blocks/CU. No barriers (wave-synchronous; per-wave DS pipe is
    // in-order, so flush-reads before next stage-writes are safe).
    __shared__ float4 sm[THREADS / 64][64 * PAD];

    const int t    = threadIdx.x;
    const int lane = t & 63;
    const int wid  = t >> 6;
    const int base = blockIdx.x * (THREADS * 2);
    const int b0   = base + t;                        // sample A
    const int b1s  = base + THREADS + t;              // sample B
    const int wb0  = base + wid * 64;                 // wave A base
    const int wb1  = base + THREADS + wid * 64;       // wave B base

    float4* const myStage = &sm[wid][lane * PAD];
    float4* const outv = reinterpret_cast<float4*>(out);

    // Precompute flush mapping once (identical for every flush):
    // G = j*64 + lane; s = G/12 (sample in wave), q = G%12 (float4 in chunk).
    // Advance G by 64 <=> s += 5, q += 4 with carry.
    int su[CUNITS], ro[CUNITS];
    {
        int s = lane / CUNITS;
        int q = lane - s * CUNITS;
        #pragma unroll
        for (int j = 0; j < CUNITS; ++j) {
            su[j] = s * PAD + q;   // LDS float4 index within wave's buffer
            ro[j] = s * 36 + q;    // out float4 offset rel. to wave base
            s += 5; q += 4;
            if (q >= CUNITS) { q -= CUNITS; s += 1; }
        }
    }

    // Load both samples' 24 x-values (96 B contiguous, 16B-aligned each).
    float xr0[NJ], xr1[NJ];
    {
        const float4* xv0 = reinterpret_cast<const float4*>(x + (size_t)b0 * NJ);
        const float4* xv1 = reinterpret_cast<const float4*>(x + (size_t)b1s * NJ);
        #pragma unroll
        for (int c = 0; c < NJ / 4; ++c) {
            float4 v0 = xv0[c];
            xr0[c * 4 + 0] = v0.x; xr0[c * 4 + 1] = v0.y;
            xr0[c * 4 + 2] = v0.z; xr0[c * 4 + 3] = v0.w;
            float4 v1 = xv1[c];
            xr1[c * 4 + 0] = v1.x; xr1[c * 4 + 1] = v1.y;
            xr1[c * 4 + 2] = v1.z; xr1[c * 4 + 3] = v1.w;
        }
    }

    float feats0[NJ][FS], feats1[NJ][FS];  // fully unrolled -> registers

    #pragma unroll
    for (int c = 0; c < 3; ++c) {
        // Sample A: compute 8 joints (staging pairs), then flush its chunk.
        #pragma unroll
        for (int i = c * 8; i < c * 8 + 8; ++i) JOINT(i, xr0, feats0, myStage);
        FLUSH(wb0, c);
        // Sample B: independent fmac chains schedule into flush A's shadow.
        #pragma unroll
        for (int i = c * 8; i < c * 8 + 8; ++i) JOINT(i, xr1, feats1, myStage);
        FLUSH(wb1, c);
    }
    (void)B;
}

extern "C" void kernel_launch(void* const* d_in, const int* in_sizes, int n_in,
                              void* d_out, int out_size, void* d_ws, size_t ws_size,
                              hipStream_t stream) {
    const float* x  = (const float*)d_in[0];
    const float* W1 = (const float*)d_in[1];
    const float* b1 = (const float*)d_in[2];
    const float* W2 = (const float*)d_in[3];
    const float* b2 = (const float*)d_in[4];
    float* out = (float*)d_out;
    const int B = in_sizes[0] / NJ;   // 524288, multiple of 512
    const int grid = B / (THREADS * 2);
    hipLaunchKernelGGL(se1d_kernel, dim3(grid), dim3(THREADS), 0, stream,
                       x, W1, b1, W2, b2, out, B);
}

// Round 6
// 162.368 us; speedup vs baseline: 1.4122x; 1.4122x over previous
//
#include <hip/hip_runtime.h>

#define NJ 24
#define NF 7
#define FS 6
#define THREADS 256
#define CUNITS 12   // float4 per thread per chunk (4 joint-pairs = 192 B)
#define PAD 13      // LDS stride in float4 units

// parent of each joint; parents[i] < i, so sequential order is topological
__device__ constexpr int kParents[NJ] = {-1, 0, 0, 0, 1, 2, 3, 4, 5, 6, 7, 8,
                                          9, 9, 9, 12, 13, 14, 16, 17, 18, 19, 20, 21};

// Compute joint i; stage completed joint-pairs (3 x float4) into LDS.
#define JOINT(i)                                                              \
    {                                                                         \
        const int p_ = kParents[i];                                           \
        float inp_[NF];                                                       \
        inp_[0] = xr[i];                                                      \
        _Pragma("unroll")                                                     \
        for (int j = 0; j < FS; ++j)                                          \
            inp_[1 + j] = (p_ < 0) ? 0.0f : feats[(p_ < 0) ? 0 : p_][j];      \
        float h_[NF];                                                         \
        _Pragma("unroll")                                                     \
        for (int j = 0; j < NF; ++j) h_[j] = b1[(i) * NF + j];                \
        _Pragma("unroll")                                                     \
        for (int k = 0; k < NF; ++k) {                                        \
            const float a_ = inp_[k];                                         \
            _Pragma("unroll")                                                 \
            for (int j = 0; j < NF; ++j)                                      \
                h_[j] = fmaf(a_, W1[(i) * NF * NF + k * NF + j], h_[j]);      \
        }                                                                     \
        _Pragma("unroll")                                                     \
        for (int j = 0; j < NF; ++j) h_[j] = fmaxf(h_[j], 0.0f);              \
        float f_[FS];                                                         \
        _Pragma("unroll")                                                     \
        for (int j = 0; j < FS; ++j) f_[j] = b2[(i) * FS + j];                \
        _Pragma("unroll")                                                     \
        for (int k = 0; k < NF; ++k) {                                        \
            const float a_ = h_[k];                                           \
            _Pragma("unroll")                                                 \
            for (int j = 0; j < FS; ++j)                                      \
                f_[j] = fmaf(a_, W2[(i) * NF * FS + k * FS + j], f_[j]);      \
        }                                                                     \
        _Pragma("unroll")                                                     \
        for (int j = 0; j < FS; ++j) {                                        \
            f_[j] = fmaxf(f_[j], 0.0f);                                       \
            feats[i][j] = f_[j];                                              \
        }                                                                     \
        if ((i) & 1) {                                                        \
            const int pp_ = ((i) >> 1) & 3;                                   \
            float4* st_ = myStage + pp_ * 3;                                  \
            st_[0] = make_float4(feats[(i) - 1][0], feats[(i) - 1][1],        \
                                 feats[(i) - 1][2], feats[(i) - 1][3]);       \
            st_[1] = make_float4(feats[(i) - 1][4], feats[(i) - 1][5],        \
                                 f_[0], f_[1]);                               \
            st_[2] = make_float4(f_[2], f_[3], f_[4], f_[5]);                 \
        }                                                                     \
    }

// Read the wave's fully-staged chunk (12 float4) into registers.
#define READ12()                                                              \
    {                                                                         \
        _Pragma("unroll")                                                     \
        for (int j = 0; j < CUNITS; ++j) fr[j] = sm[wid][su[j]];              \
    }

// Issue 3 of the chunk's 12 stores (each wave-store = 16 full 64B lines).
#define STORE3(J, C)                                                          \
    {                                                                         \
        _Pragma("unroll")                                                     \
        for (int j = (J); j < (J) + 3; ++j)                                   \
            outv[(size_t)wb * 36 + (C) * 12 + ro[j]] = fr[j];                 \
    }

// Requires B % 256 == 0 (bench: B = 524288).
__global__ __launch_bounds__(THREADS, 3) void se1d_kernel(
    const float* __restrict__ x,
    const float* __restrict__ W1,
    const float* __restrict__ b1,
    const float* __restrict__ W2,
    const float* __restrict__ b2,
    float* __restrict__ out, int B)
{
    // Wave-private staging: 64 lanes x 13 float4 = 13312 B/wave, 53 KB/block
    // -> 3 blocks/CU (12 waves). No barriers: wave-synchronous, and the
    // per-wave DS pipe is in-order, so chunk-c ds_reads issued before
    // chunk-(c+1) stage-writes return the old (correct) data.
    __shared__ float4 sm[THREADS / 64][64 * PAD];

    const int t    = threadIdx.x;
    const int lane = t & 63;
    const int wid  = t >> 6;
    const int b    = blockIdx.x * THREADS + t;         // this thread's sample
    const int wb   = blockIdx.x * THREADS + wid * 64;  // wave's sample base

    float4* const myStage = &sm[wid][lane * PAD];
    float4* const outv = reinterpret_cast<float4*>(out);

    // Flush mapping, identical for every chunk:
    // G = j*64 + lane; s = G/12 (sample in wave), q = G%12 (float4 in chunk).
    // Advance G by 64 <=> s += 5, q += 4 with carry.
    int su[CUNITS], ro[CUNITS];
    {
        int s = lane / CUNITS;
        int q = lane - s * CUNITS;
        #pragma unroll
        for (int j = 0; j < CUNITS; ++j) {
            su[j] = s * PAD + q;   // LDS float4 index within wave's buffer
            ro[j] = s * 36 + q;    // out float4 offset rel. to wave base
            s += 5; q += 4;
            if (q >= CUNITS) { q -= CUNITS; s += 1; }
        }
    }

    // Load this sample's 24 x-values (96 B contiguous, 16B-aligned).
    float xr[NJ];
    {
        const float4* xv = reinterpret_cast<const float4*>(x + (size_t)b * NJ);
        #pragma unroll
        for (int c = 0; c < NJ / 4; ++c) {
            float4 v = xv[c];
            xr[c * 4 + 0] = v.x; xr[c * 4 + 1] = v.y;
            xr[c * 4 + 2] = v.z; xr[c * 4 + 3] = v.w;
        }
    }

    float feats[NJ][FS];  // fully unrolled -> registers, ~3 joints live
    float4 fr[CUNITS];    // chunk flush data held in registers

    // chunk 0: compute + stage
    JOINT(0) JOINT(1) JOINT(2) JOINT(3) JOINT(4) JOINT(5) JOINT(6) JOINT(7)
    READ12();
    // chunk 1 compute, chunk 0 stores dribbled after each joint-pair
    JOINT(8)  JOINT(9)  STORE3(0, 0);
    JOINT(10) JOINT(11) STORE3(3, 0);
    JOINT(12) JOINT(13) STORE3(6, 0);
    JOINT(14) JOINT(15) STORE3(9, 0);
    READ12();
    // chunk 2 compute, chunk 1 stores dribbled
    JOINT(16) JOINT(17) STORE3(0, 1);
    JOINT(18) JOINT(19) STORE3(3, 1);
    JOINT(20) JOINT(21) STORE3(6, 1);
    JOINT(22) JOINT(23) STORE3(9, 1);
    READ12();
    // chunk 2 stores
    STORE3(0, 2); STORE3(3, 2); STORE3(6, 2); STORE3(9, 2);
    (void)B;
}

extern "C" void kernel_launch(void* const* d_in, const int* in_sizes, int n_in,
                              void* d_out, int out_size, void* d_ws, size_t ws_size,
                              hipStream_t stream) {
    const float* x  = (const float*)d_in[0];
    const float* W1 = (const float*)d_in[1];
    const float* b1 = (const float*)d_in[2];
    const float* W2 = (const float*)d_in[3];
    const float* b2 = (const float*)d_in[4];
    float* out = (float*)d_out;
    const int B = in_sizes[0] / NJ;   // 524288, multiple of 256
    const int grid = B / THREADS;
    hipLaunchKernelGGL(se1d_kernel, dim3(grid), dim3(THREADS), 0, stream,
                       x, W1, b1, W2, b2, out, B);
}